// Round 1
// baseline (6025.659 us; speedup 1.0000x reference)
//
#include <hip/hip_runtime.h>
#include <math.h>

#define B_ 32
#define T_ 128
#define D_ 512
#define U_ 512
#define G_ 2048   // 4U
#define NWGB 8    // workgroups per batch
#define GK 512    // K dim of precompute GEMMs

// ---------------------------------------------------------------------------
// Precompute GEMM: C[M,N] = A[M,512] @ W[512,N] + bias[N]
// A = x viewed as (B*T, D). 64x64 tile, 256 threads, 4x4 register tile.
// ---------------------------------------------------------------------------
__global__ __launch_bounds__(256) void gemm_bias(const float* __restrict__ A,
                                                 const float* __restrict__ W,
                                                 const float* __restrict__ bias,
                                                 float* __restrict__ C, int N) {
  __shared__ float As[16][68];  // [k][row], padded
  __shared__ float Ws[16][64];  // [k][col]
  const int tid = threadIdx.x;
  const int rowbase = blockIdx.y * 64;
  const int colbase = blockIdx.x * 64;
  const int ty = tid >> 4, tx = tid & 15;
  const int ar = tid >> 2, ak = (tid & 3) << 2;
  const int wk = tid >> 4, wc = (tid & 15) << 2;
  float acc[4][4] = {{0.f, 0.f, 0.f, 0.f}};
  for (int k0 = 0; k0 < GK; k0 += 16) {
    float4 av = *(const float4*)(A + (size_t)(rowbase + ar) * GK + k0 + ak);
    float4 wv = *(const float4*)(W + (size_t)(k0 + wk) * N + colbase + wc);
    __syncthreads();  // protect previous iteration's reads
    As[ak + 0][ar] = av.x;
    As[ak + 1][ar] = av.y;
    As[ak + 2][ar] = av.z;
    As[ak + 3][ar] = av.w;
    *(float4*)(&Ws[wk][wc]) = wv;
    __syncthreads();
#pragma unroll
    for (int kk = 0; kk < 16; ++kk) {
      float4 a = *(const float4*)(&As[kk][ty << 2]);
      float4 wv2 = *(const float4*)(&Ws[kk][tx << 2]);
      float a4[4] = {a.x, a.y, a.z, a.w};
      float w4[4] = {wv2.x, wv2.y, wv2.z, wv2.w};
#pragma unroll
      for (int i = 0; i < 4; ++i)
#pragma unroll
        for (int jj = 0; jj < 4; ++jj) acc[i][jj] += a4[i] * w4[jj];
    }
  }
  float4 bv = *(const float4*)(bias + colbase + (tx << 2));
#pragma unroll
  for (int i = 0; i < 4; ++i) {
    float4 o;
    o.x = acc[i][0] + bv.x;
    o.y = acc[i][1] + bv.y;
    o.z = acc[i][2] + bv.z;
    o.w = acc[i][3] + bv.w;
    *(float4*)(C + (size_t)(rowbase + (ty << 2) + i) * N + colbase + (tx << 2)) = o;
  }
}

// ---------------------------------------------------------------------------
// Transpose att_x (B,T,U) -> att_xT (B,U,T) so the per-step tanh reduction
// reads coalesced along T.
// ---------------------------------------------------------------------------
__global__ __launch_bounds__(256) void transpose_tu(const float* __restrict__ in,
                                                    float* __restrict__ outp) {
  __shared__ float tile[32][33];
  const int b = blockIdx.y;
  const int tt0 = (blockIdx.x & 3) * 32;   // T/32 = 4
  const int uu0 = (blockIdx.x >> 2) * 32;  // U/32 = 16
  const int lx = threadIdx.x & 31, ly = threadIdx.x >> 5;  // 32 x 8
#pragma unroll
  for (int qq = 0; qq < 4; ++qq) {
    int tt = tt0 + ly + qq * 8;
    tile[ly + qq * 8][lx] = in[((size_t)b * T_ + tt) * U_ + uu0 + lx];
  }
  __syncthreads();
#pragma unroll
  for (int qq = 0; qq < 4; ++qq) {
    int uu = uu0 + ly + qq * 8;
    outp[((size_t)b * U_ + uu) * T_ + tt0 + lx] = tile[lx][ly + qq * 8];
  }
}

// ---------------------------------------------------------------------------
// Per-batch spin barrier across the NWGB workgroups of one batch.
// Device-scope atomics (cross-XCD safe). Counter is monotonic; target is
// NWGB * epoch. Release on arrival publishes this WG's global writes
// (agent-scope release ⇒ L2 writeback); acquire on the spin load invalidates
// stale L1/L2 before the post-barrier reads.
// ---------------------------------------------------------------------------
__device__ inline void batch_barrier(unsigned* ctr, unsigned target) {
  __syncthreads();  // compiler drains vmem before s_barrier → stores are in L2
  if (threadIdx.x == 0) {
    __hip_atomic_fetch_add(ctr, 1u, __ATOMIC_RELEASE, __HIP_MEMORY_SCOPE_AGENT);
    while (__hip_atomic_load(ctr, __ATOMIC_ACQUIRE, __HIP_MEMORY_SCOPE_AGENT) <
           target) {
      __builtin_amdgcn_s_sleep(2);
    }
  }
  __syncthreads();
}

// ---------------------------------------------------------------------------
// Recurrence: grid = 32 batches x 8 WGs, 256 threads.
// WG (b,g): owns u-slice [g*64, g*64+64) for hU/scores/c/h, d-slice g*64 for z,
// and gate columns {q*512 + g*64 + j}. 3 per-batch barriers per step.
// ---------------------------------------------------------------------------
__global__ __launch_bounds__(256) void attlstm_rec(
    const float* __restrict__ x,       // (B,T,D)
    const float* __restrict__ xk,      // (B,T,4U)  x@kernel + bias
    const float* __restrict__ attxT,   // (B,U,T)   (x@attW + attb)^T
    const float* __restrict__ Rk,      // (U,4U)    recurrent_kernel
    const float* __restrict__ Ak,      // (D,4U)    attention_kernel
    const float* __restrict__ Um,      // (U,U)     attention_U
    const float* __restrict__ V,       // (U)       attention_V
    float* __restrict__ h_g,           // (B,U)
    float* __restrict__ sp_g,          // (B,8,T) score partials
    float* __restrict__ z_g,           // (B,D)
    unsigned* __restrict__ bars,       // (B,64) padded counters
    float* __restrict__ out) {         // (B,T,U)
  const int w = blockIdx.x;
  const int b = w >> 3;
  const int g = w & 7;
  const int tid = threadIdx.x;
  const int u0 = g * 64;
  const int q = tid >> 6;  // 0:i 1:f 2:c~ 3:o
  const int j = tid & 63;
  const int col = q * U_ + u0 + j;

  __shared__ float h_s[U_];
  __shared__ float z_s[D_];
  __shared__ float hU_s[64];
  __shared__ float sc_s[T_];
  __shared__ float red_s[4][64];
  __shared__ float red2_s[2][T_];
  __shared__ float gate_s[4][64];
  __shared__ float c_s[64];
  __shared__ float Vs[64];
  __shared__ float m_sh, l_sh;

  for (int i = tid; i < U_; i += 256) h_s[i] = 0.f;
  if (tid < 64) {
    c_s[tid] = 0.f;
    Vs[tid] = V[u0 + tid];
  }
  unsigned* ctr = bars + (size_t)b * 64;
  unsigned epoch = 0;
  __syncthreads();

  for (int t = 0; t < T_; ++t) {
    // ---- P1a: hU partials (u = u0+j, v-segment q*128..q*128+128) ----
    {
      float a1 = 0.f;
      const float* Up = Um + (size_t)(q * 128) * U_ + u0 + j;
      for (int v = 0; v < 128; ++v) a1 += h_s[q * 128 + v] * Up[(size_t)v * U_];
      red_s[q][j] = a1;
    }
    // ---- P1b: ghr = h . R[:,col]  (independent of hU; uses only h_s) ----
    float ghr = 0.f;
    {
      const float* Rp = Rk + col;
      for (int v = 0; v < U_; ++v) ghr += h_s[v] * Rp[(size_t)v * G_];
    }
    __syncthreads();
    if (tid < 64)
      hU_s[tid] = red_s[0][tid] + red_s[1][tid] + red_s[2][tid] + red_s[3][tid];
    __syncthreads();
    // ---- P1c: score partials over this WG's u-slice, all t' ----
    {
      const int tt = tid & 127;
      const int half = tid >> 7;
      const float* ap = attxT + ((size_t)b * U_ + u0 + half * 32) * T_ + tt;
      float s = 0.f;
      for (int uu = 0; uu < 32; ++uu) {
        int u = half * 32 + uu;
        float e = tanhf(ap[(size_t)uu * T_] + hU_s[u]);
        s += e * Vs[u];
      }
      red2_s[half][tt] = s;
    }
    __syncthreads();
    if (tid < T_)
      sp_g[((size_t)b * NWGB + g) * T_ + tid] = red2_s[0][tid] + red2_s[1][tid];
    batch_barrier(ctr, NWGB * (++epoch));  // B1: score partials visible

    // ---- P2: full scores, softmax over T, z slice ----
    if (tid < T_) {
      float s = 0.f;
      for (int gg = 0; gg < NWGB; ++gg)
        s += sp_g[((size_t)b * NWGB + gg) * T_ + tid];
      sc_s[tid] = s;
    }
    __syncthreads();
    if (tid < 64) {
      float v2 = fmaxf(sc_s[tid], sc_s[tid + 64]);
      for (int o = 32; o > 0; o >>= 1) v2 = fmaxf(v2, __shfl_down(v2, o));
      if (tid == 0) m_sh = v2;
    }
    __syncthreads();
    if (tid < T_) sc_s[tid] = __expf(sc_s[tid] - m_sh);
    __syncthreads();
    if (tid < 64) {
      float v2 = sc_s[tid] + sc_s[tid + 64];
      for (int o = 32; o > 0; o >>= 1) v2 += __shfl_down(v2, o);
      if (tid == 0) l_sh = v2;
    }
    __syncthreads();
    {  // z[d0+j] partial over t-segment q
      const float* xp = x + ((size_t)b * T_ + q * 32) * D_ + u0 + j;
      float zz = 0.f;
      for (int t2 = 0; t2 < 32; ++t2) zz += sc_s[q * 32 + t2] * xp[(size_t)t2 * D_];
      red_s[q][j] = zz;
    }
    __syncthreads();
    if (tid < 64)
      z_g[(size_t)b * D_ + u0 + tid] =
          (red_s[0][tid] + red_s[1][tid] + red_s[2][tid] + red_s[3][tid]) / l_sh;
    batch_barrier(ctr, NWGB * (++epoch));  // B2: z visible

    // ---- P3: gates, LSTM update ----
    for (int i = tid; i < D_; i += 256) z_s[i] = z_g[(size_t)b * D_ + i];
    __syncthreads();
    float gza = 0.f;
    {
      const float* Ap = Ak + col;
      for (int v = 0; v < D_; ++v) gza += z_s[v] * Ap[(size_t)v * G_];
    }
    float gate = xk[((size_t)b * T_ + t) * G_ + col] + ghr + gza;
    float gv;
    if (q == 2)
      gv = tanhf(gate);
    else
      gv = fminf(fmaxf(0.2f * gate + 0.5f, 0.f), 1.f);  // hard_sigmoid
    gate_s[q][j] = gv;
    __syncthreads();
    if (tid < 64) {
      float cn = gate_s[1][tid] * c_s[tid] + gate_s[0][tid] * gate_s[2][tid];
      c_s[tid] = cn;
      float hn = gate_s[3][tid] * tanhf(cn);
      h_g[(size_t)b * U_ + u0 + tid] = hn;
      out[((size_t)b * T_ + t) * U_ + u0 + tid] = hn;
    }
    batch_barrier(ctr, NWGB * (++epoch));  // B3: h_new visible
    for (int i = tid; i < U_; i += 256) h_s[i] = h_g[(size_t)b * U_ + i];
    __syncthreads();
  }
}

// ---------------------------------------------------------------------------
extern "C" void kernel_launch(void* const* d_in, const int* in_sizes, int n_in,
                              void* d_out, int out_size, void* d_ws,
                              size_t ws_size, hipStream_t stream) {
  (void)in_sizes;
  (void)n_in;
  (void)out_size;
  (void)ws_size;
  const float* x = (const float*)d_in[0];
  const float* Wk = (const float*)d_in[1];    // kernel (D,4U)
  const float* Rk = (const float*)d_in[2];    // recurrent_kernel (U,4U)
  const float* Ak = (const float*)d_in[3];    // attention_kernel (D,4U)
  const float* Wa = (const float*)d_in[4];    // attention_W (D,U)
  const float* Ua = (const float*)d_in[5];    // attention_U (U,U)
  const float* Va = (const float*)d_in[6];    // attention_V (U,1)
  const float* bias = (const float*)d_in[7];  // (4U)
  const float* ba = (const float*)d_in[8];    // attention_b (U)
  float* out = (float*)d_out;

  char* ws = (char*)d_ws;
  float* xk = (float*)(ws);                  // B*T*4U floats = 32 MiB
  float* attx = (float*)(ws + 33554432);     // B*T*U = 8 MiB
  float* attxT = (float*)(ws + 41943040);    // B*U*T = 8 MiB
  float* h_g = (float*)(ws + 50331648);      // B*U
  float* sp_g = (float*)(ws + 50397184);     // B*8*T
  float* z_g = (float*)(ws + 50528256);      // B*D
  unsigned* bars = (unsigned*)(ws + 50593792);  // B*64 u32

  // Precompute: xk = x@kernel + bias ; att_x = x@attW + attb ; transpose.
  gemm_bias<<<dim3(G_ / 64, (B_ * T_) / 64), 256, 0, stream>>>(x, Wk, bias, xk, G_);
  gemm_bias<<<dim3(U_ / 64, (B_ * T_) / 64), 256, 0, stream>>>(x, Wa, ba, attx, U_);
  transpose_tu<<<dim3(64, B_), 256, 0, stream>>>(attx, attxT);
  hipMemsetAsync(bars, 0, B_ * 64 * sizeof(unsigned), stream);

  // Recurrence: 32 batches x 8 WGs, per-batch barriers only (no grid sync).
  attlstm_rec<<<dim3(B_ * NWGB), dim3(256), 0, stream>>>(
      x, xk, attxT, Rk, Ak, Ua, Va, h_g, sp_g, z_g, bars, out);
}